// Round 5
// baseline (4199.476 us; speedup 1.0000x reference)
//
#include <hip/hip_runtime.h>

// ContinuousLSTMLayer B=256,S=512,F=64,H=128; 8192 sequential RK4 stages.
// MFMA broadcast-A persistent kernel, v2:
//  - Only h-part weight B-frags resident in VGPRs (4 gates x 4 ktiles = 64
//    regs; was 96 incl. x-part -> compiler pushed them to AGPRs and emitted
//    ~64 v_accvgpr_read copies per stage = the round-4 VALU excess).
//  - x-part B-frags live in LDS in fragment order (64 KB), read once per
//    time step (amortized over 16 stages).
//  - Per-gate MFMA tree flattened: 4 independent depth-1 MFMAs + 3-add tree
//    (cuts one MFMA latency from the serial path).
// Broadcast-A trick: all lanes read the same h chunk, so D is replicated and
// lane's n = 16*wave + (lane&15) gets i,f,o,g locally; 1 barrier per stage.

#define B_N 256
#define S_N 512
#define F_N 64
#define H_N 128

typedef _Float16 v8h __attribute__((ext_vector_type(8)));
typedef float v4f __attribute__((ext_vector_type(4)));

// sigmoid via exp2 + rcp (overflow-safe: rcp(inf)=0)
static __device__ __forceinline__ float sigm(float x) {
  float e = __builtin_amdgcn_exp2f(-1.442695040888963f * x);
  return __builtin_amdgcn_rcpf(1.0f + e);
}

__global__ void __launch_bounds__(512, 2) clstm_mfma2(
    const float* __restrict__ x,    // [B,S,F] f32
    const float* __restrict__ td,   // [B,S]   f32
    const float* __restrict__ Wi, const float* __restrict__ bi,
    const float* __restrict__ Wf, const float* __restrict__ bff,
    const float* __restrict__ Wo, const float* __restrict__ bo,
    const float* __restrict__ Wg, const float* __restrict__ bg,
    float* __restrict__ out)        // [B,S,H] f32
{
  const int b    = blockIdx.x;
  const int t    = threadIdx.x;
  const int wv   = t >> 6;     // wave 0..7 -> n-tile
  const int l    = t & 63;
  const int col  = l & 15;     // n within tile
  const int quad = l >> 4;     // k sub-chunk selector (A/B frag layout)
  const int n    = wv * 16 + col;

  const float* Wptr[4] = {Wi, Wf, Wo, Wg};

  // ---- resident h-part B-frags: Bh[gate][kt], comb rows 64+kt*32..64+kt*32+31
  // lane holds B[k = quad*8 + j][n] as 8 f16 (4 VGPRs). 64 VGPRs total.
  v8h Bh[4][4];
#pragma unroll
  for (int g = 0; g < 4; ++g) {
    const float* W = Wptr[g];
#pragma unroll
    for (int kt = 0; kt < 4; ++kt) {
      v8h f;
#pragma unroll
      for (int j = 0; j < 8; ++j)
        f[j] = (_Float16)W[(64 + kt * 32 + quad * 8 + j) * H_N + n];
      Bh[g][kt] = f;
    }
  }
  v4f cb[4];  // bias as all-equal C operand
#pragma unroll
  for (int g = 0; g < 4; ++g) {
    float bv = (g == 0 ? bi : g == 1 ? bff : g == 2 ? bo : bg)[n];
    cb[g][0] = bv; cb[g][1] = bv; cb[g][2] = bv; cb[g][3] = bv;
  }

  // ---- LDS: x-part B-frags in fragment order [g*2+kt][tid] (64 KB), plus
  // double-buffered h, current x_t, time_diffs.
  __shared__ alignas(16) v8h lds_wx[8][512];
  __shared__ alignas(16) _Float16 lds_h[2][H_N];
  __shared__ alignas(16) _Float16 lds_x[F_N];
  __shared__ float lds_td[S_N];

#pragma unroll
  for (int g = 0; g < 4; ++g) {
    const float* W = Wptr[g];
#pragma unroll
    for (int kt = 0; kt < 2; ++kt) {
      v8h f;
#pragma unroll
      for (int j = 0; j < 8; ++j)
        f[j] = (_Float16)W[(kt * 32 + quad * 8 + j) * H_N + n];
      lds_wx[g * 2 + kt][t] = f;
    }
  }
  lds_td[t] = td[b * S_N + t];
  if (t < 32) {
    const float* xr = x + (size_t)b * S_N * F_N;
    lds_x[2 * t]     = (_Float16)xr[2 * t];
    lds_x[2 * t + 1] = (_Float16)xr[2 * t + 1];
  }
  if (t < H_N) lds_h[0][t] = (_Float16)0.0f;
  __syncthreads();

  float h0v = 0.f, c0v = 0.f;      // RK base state for n (replicated x4 quads)
  float h_ev = 0.f, c_ev = 0.f;
  float sum_h = 0.f, sum_c = 0.f;
  const v4f zf = {0.f, 0.f, 0.f, 0.f};

  for (int s = 0; s < S_N; ++s) {
    float dt  = fminf(lds_td[s], 1.0f) * 0.25f;  // MAX_DT / ODE_STEPS
    float hdt = 0.5f * dt;
    float d6  = dt * (1.0f / 6.0f);

    // x-projection + bias once per time step (frags from LDS; amortized /16)
    v8h ax0 = *(const v8h*)(lds_x + quad * 8);
    v8h ax1 = *(const v8h*)(lds_x + 32 + quad * 8);
    v4f xpD[4];
#pragma unroll
    for (int g = 0; g < 4; ++g) {
      v8h b0 = lds_wx[g * 2 + 0][t];
      v8h b1 = lds_wx[g * 2 + 1][t];
      v4f a = __builtin_amdgcn_mfma_f32_16x16x32_f16(ax0, b0, cb[g], 0, 0, 0);
      xpD[g] = __builtin_amdgcn_mfma_f32_16x16x32_f16(ax1, b1, a, 0, 0, 0);
    }

    // prefetch next x row into regs (consumed at last stage of this step)
    float xn0 = 0.f, xn1 = 0.f;
    if (t < 32 && s + 1 < S_N) {
      const float* xr = x + (size_t)(b * S_N + s + 1) * F_N;
      xn0 = xr[2 * t]; xn1 = xr[2 * t + 1];
    }

#pragma unroll 1
    for (int ode = 0; ode < 4; ++ode) {
#pragma unroll
      for (int st = 0; st < 4; ++st) {
        const _Float16* hb = lds_h[st & 1];
        // broadcast A-frags: lane holds h[kt*32 + quad*8 + j]
        v8h ah0 = *(const v8h*)(hb + quad * 8);
        v8h ah1 = *(const v8h*)(hb + 32 + quad * 8);
        v8h ah2 = *(const v8h*)(hb + 64 + quad * 8);
        v8h ah3 = *(const v8h*)(hb + 96 + quad * 8);
        // per gate: 4 independent depth-1 MFMAs + add tree
        float pre[4];
#pragma unroll
        for (int g = 0; g < 4; ++g) {
          v4f d0 = __builtin_amdgcn_mfma_f32_16x16x32_f16(ah0, Bh[g][0], xpD[g], 0, 0, 0);
          v4f d1 = __builtin_amdgcn_mfma_f32_16x16x32_f16(ah1, Bh[g][1], zf, 0, 0, 0);
          v4f d2 = __builtin_amdgcn_mfma_f32_16x16x32_f16(ah2, Bh[g][2], zf, 0, 0, 0);
          v4f d3 = __builtin_amdgcn_mfma_f32_16x16x32_f16(ah3, Bh[g][3], zf, 0, 0, 0);
          pre[g] = (d0[0] + d1[0]) + (d2[0] + d3[0]);
        }
        float ai = sigm(pre[0]);
        float af = sigm(pre[1]);
        float ao = sigm(pre[2]);
        float ag = fmaf(2.0f, sigm(2.0f * pre[3]), -1.0f);   // tanh
        float tc = fmaf(2.0f, sigm(2.0f * c_ev), -1.0f);     // tanh(c)
        float kc = fmaf(ai, ag, (af - 1.0f) * c_ev);         // i*g + f*c - c
        float kh = fmaf(ao, tc, -h_ev);                      // o*tanh(c) - h

        float h_nx, c_nx;
        if (st == 0) {
          sum_h = kh; sum_c = kc;
          h_nx = fmaf(hdt, kh, h0v); c_nx = fmaf(hdt, kc, c0v);
        } else if (st == 1) {
          sum_h = fmaf(2.f, kh, sum_h); sum_c = fmaf(2.f, kc, sum_c);
          h_nx = fmaf(hdt, kh, h0v); c_nx = fmaf(hdt, kc, c0v);
        } else if (st == 2) {
          sum_h = fmaf(2.f, kh, sum_h); sum_c = fmaf(2.f, kc, sum_c);
          h_nx = fmaf(dt, kh, h0v); c_nx = fmaf(dt, kc, c0v);
        } else {
          sum_h += kh; sum_c += kc;
          h0v = fmaf(d6, sum_h, h0v); c0v = fmaf(d6, sum_c, c0v);
          h_nx = h0v; c_nx = c0v;
        }

        if (quad == 0) lds_h[(st & 1) ^ 1][n] = (_Float16)h_nx;  // 128 writers
        if (st == 3 && ode == 3 && t < 32 && s + 1 < S_N) {
          lds_x[2 * t]     = (_Float16)xn0;
          lds_x[2 * t + 1] = (_Float16)xn1;
        }
        __syncthreads();
        h_ev = h_nx; c_ev = c_nx;
      }
    }

    if (quad == 0) out[(size_t)(b * S_N + s) * H_N + n] = h0v;
  }
}

extern "C" void kernel_launch(void* const* d_in, const int* in_sizes, int n_in,
                              void* d_out, int out_size, void* d_ws, size_t ws_size,
                              hipStream_t stream) {
  (void)in_sizes; (void)n_in; (void)d_ws; (void)ws_size; (void)out_size;
  clstm_mfma2<<<B_N, 512, 0, stream>>>(
      (const float*)d_in[0],  // x
      (const float*)d_in[1],  // time_diffs
      (const float*)d_in[2], (const float*)d_in[3],   // W_i, b_i
      (const float*)d_in[4], (const float*)d_in[5],   // W_f, b_f
      (const float*)d_in[6], (const float*)d_in[7],   // W_o, b_o
      (const float*)d_in[8], (const float*)d_in[9],   // W_g, b_g
      (float*)d_out);
}